// Round 1
// baseline (232.444 us; speedup 1.0000x reference)
//
#include <hip/hip_runtime.h>
#include <hip/hip_cooperative_groups.h>

namespace cg = cooperative_groups;

#define T_N     1048576
#define BLK     256
#define S_OUT   8
#define R_BLOCK (BLK * S_OUT)        // 2048 rows per block
#define NB      (T_N / R_BLOCK)      // 512 blocks == 2 blocks/CU -> cooperative-safe
#define WARM    64                   // 0.71^64 ~ 3e-10: bias*1e5 rows stays ~5e-5 (do NOT shrink)
#define HALO    (WARM + 4)           // warm-up + max shift
#define SW(u)   ((u) + ((u) >> 3))   // LDS swizzle: stride 8 -> 9, gcd(9,32)=1, conflict-free

__device__ __forceinline__ float pp_step(float c, float p, float mr, float miss,
                                         float omev, float evc) {
    float last = (c > mr) ? fmaf(c - mr, miss, mr) : c;
    return fmaf(last + p, omev, -evc);
}

// Single cooperative kernel: phase A computes per-thread outputs in registers +
// block aggregates; grid.sync(); phase B folds the cross-block recurrence carry
// into the registers and stores out exactly once. Removes: 2nd launch, the 8 MB
// out re-read/modify/write of the old k_fix, and the 1 MB Bthr round-trip.
__global__ __launch_bounds__(BLK, 2) void k_fused(
    const float* __restrict__ x,
    const float* __restrict__ f0p, const float* __restrict__ fcp,
    const float* __restrict__ kp,  const float* __restrict__ nnp,
    const float* __restrict__ dpp, const float* __restrict__ evp,
    const float* __restrict__ evcp,const float* __restrict__ mrp,
    const float* __restrict__ missp,
    const float* __restrict__ wr1p,const float* __restrict__ wr2p,
    const float* __restrict__ wz1p,const float* __restrict__ wz2p,
    const int*   __restrict__ epp,
    float* __restrict__ out, float* __restrict__ Bblk)
{
    __shared__ float s_prec[SW(R_BLOCK + HALO - 1) + 1];
    __shared__ float s_cG[SW(R_BLOCK + 3) + 1];
    __shared__ float s_cA[SW(R_BLOCK + 3) + 1];
    __shared__ float s_B[BLK];
    __shared__ float sBb[NB];
    __shared__ float sred[BLK];
    __shared__ float carr[BLK];
    // total LDS ~33.1 KB -> 4 blocks/CU by LDS; __launch_bounds__(256,2) caps
    // VGPR at 128 so >=2 blocks/CU by registers: 512-block cooperative grid fits.

    const int b = blockIdx.x, t = threadIdx.x;
    const int row0 = b * R_BLOCK;

    const float f0 = *f0p, fc = *fcp, kk = *kp, nn = *nnp;
    const float dp = *dpp, ev = *evp, evc = *evcp, mr = *mrp, miss = *missp;
    const float wr1 = *wr1p, wr2 = *wr2p, wz1 = *wz1p, wz2 = *wz2p;
    const int ep = *epp;
    const float omev = 1.0f - ev;
    const float cimp = 1.49f / nn;
    const float f0mfc = f0 - fc;

    const float rid = rintf(x[8]);                    // jnp.round == rint (half-even)
    const int shift = (rid == 3723.0f || rid == 870.0f) ? 1 : 4;
    const float pp0 = x[7] - x[6];                    // total_prec[0] - prec[0]

    // Stage prec column (scan-1 input) with warm-up halo. Rows are 36 B; every
    // 64 B line holds needed data -> 36 MB total fetch is the floor.
    for (int u = t; u < R_BLOCK + HALO; u += BLK) {
        int r = row0 - HALO + u;
        s_prec[SW(u)] = (r >= 0) ? x[r * 9 + 6] : 0.0f;
    }
    // Stage per-row q coefficients for rows [row0-4, row0+R_BLOCK).
    for (int u = t; u < R_BLOCK + 4; u += BLK) {
        int r = row0 - 4 + u;
        float cg_ = 0.0f, ca = 0.0f;
        if (r >= 0) {
            const float* row = x + r * 9;
            float gl = row[0], imp = row[2], ar = row[3], sl = row[4], tp = row[7];
            float ft = fmaf(f0mfc, __expf(-kk * tp), fc);
            cg_ = gl * ar * (1.0f - ft) * 0.001f;
            ca = sqrtf(imp * ar) * cimp * sqrtf(sl);
        }
        s_cG[SW(u)] = cg_;
        s_cA[SW(u)] = ca;
    }
    __syncthreads();

    // ---- scan-1: per-thread warm-up (contractive, slope <= 1-ev = 0.71/step) ----
    const int i0 = row0 + t * S_OUT;
    const int rb = i0 - shift;
    int rr = rb - WARM; if (rr < 0) rr = 0;
    float c = (rr == 0) ? pp0 : 0.0f;
    const int rs = (rb < 0) ? 0 : rb;
    for (; rr < rs; ++rr)
        c = pp_step(c, s_prec[SW(rr - row0 + HALO)], mr, miss, omev, evc);

    // ---- q + local (zero carry-in) scan-2; outputs held in registers ----
    float outl[S_OUT];
    float h = 0.0f;
    #pragma unroll
    for (int j = 0; j < S_OUT; ++j) {
        const int i = i0 + j;
        const int r = i - shift;
        float qs = 0.0f;
        if (r >= 0) {
            float pre = fmaxf(c, 0.0f);                 // relu'd prec_pre; carry stays raw
            int ci = r - row0 + 4;
            float qg = fmaxf(pre * s_cG[SW(ci)], 0.0f);
            float di = fmaxf(fmaf(pre, 0.001f, -dp), 0.0f);
            float qi = fmaxf(s_cA[SW(ci)] * __powf(di, 5.0f / 3.0f), 0.0f);
            qs = qg + qi;
            c = pp_step(c, s_prec[SW(r - row0 + HALO)], mr, miss, omev, evc);
        }
        h = fmaf(wr1, h, wr2 * qs);     // q_shift[0]=0 keeps h=0 through i=0 (matches ref)
        outl[j] = (ep > 10) ? fmaf(wz1, h, wz2 * qs) : qs;
    }

    // ---- block aggregate publish (agent-scope: per-XCD L2s are not coherent) ----
    float Bv = (ep > 10) ? h : 0.0f;    // zero when epoch<=10 -> phase B is a no-op
    s_B[t] = Bv;
    __syncthreads();
    const float at = powf(wr1, (float)S_OUT);
    if (t == 0) {
        float acc = 0.0f;
        for (int u = 0; u < BLK; ++u) acc = fmaf(at, acc, s_B[u]);
        __hip_atomic_store(&Bblk[b], acc, __ATOMIC_RELAXED, __HIP_MEMORY_SCOPE_AGENT);
    }
    __threadfence();                    // release before the grid-wide barrier
    cg::this_grid().sync();

    // ---- phase B: cross-block carry, folded into registers before the only store ----
    float hin = 0.0f;
    if (ep > 10) {                      // ep is grid-uniform: no divergence hazard
        for (int u = t; u < NB; u += BLK)
            sBb[u] = __hip_atomic_load(&Bblk[u], __ATOMIC_RELAXED, __HIP_MEMORY_SCOPE_AGENT);
        __syncthreads();
        const float ab = powf(wr1, (float)R_BLOCK);     // wr1=1 -> exactly 1
        float partial = 0.0f;
        for (int u = t; u < b; u += BLK)                // <=2 iterations
            partial = fmaf(sBb[u], powf(ab, (float)(b - 1 - u)), partial);
        sred[t] = partial;
        __syncthreads();
        for (int off = BLK / 2; off > 0; off >>= 1) {
            if (t < off) sred[t] += sred[t + off];
            __syncthreads();
        }
        // per-thread carry: serial 256-fma prefix on t0 (~0.4 us, blocks in parallel)
        if (t == 0) {
            float cth = sred[0];
            for (int u = 0; u < BLK; ++u) { carr[u] = cth; cth = fmaf(at, cth, s_B[u]); }
        }
        __syncthreads();
        hin = carr[t];
    }
    if (hin != 0.0f) {                  // epoch<=10 or true-zero carry: exact no-op
        float p = hin * wz1;
        #pragma unroll
        for (int j = 0; j < S_OUT; ++j) { p *= wr1; outl[j] += p; }
    }

    // coalesced single store: 2 x float4 per thread, 32B-aligned
    float4* op = reinterpret_cast<float4*>(out + i0);
    op[0] = make_float4(outl[0], outl[1], outl[2], outl[3]);
    op[1] = make_float4(outl[4], outl[5], outl[6], outl[7]);
}

extern "C" void kernel_launch(void* const* d_in, const int* in_sizes, int n_in,
                              void* d_out, int out_size, void* d_ws, size_t ws_size,
                              hipStream_t stream) {
    const float* x    = (const float*)d_in[0];
    const float* f0p  = (const float*)d_in[1];
    const float* fcp  = (const float*)d_in[2];
    const float* kp   = (const float*)d_in[3];
    const float* nnp  = (const float*)d_in[4];
    const float* dpp  = (const float*)d_in[5];
    const float* evp  = (const float*)d_in[6];
    const float* evcp = (const float*)d_in[7];
    const float* mrp  = (const float*)d_in[8];
    const float* missp= (const float*)d_in[9];
    const float* wr1p = (const float*)d_in[10];
    const float* wr2p = (const float*)d_in[11];
    const float* wz1p = (const float*)d_in[12];
    const float* wz2p = (const float*)d_in[13];
    const int*   epp  = (const int*)d_in[14];
    float* out  = (float*)d_out;
    float* Bblk = (float*)d_ws;            // NB floats (2 KB)

    void* args[] = { &x, &f0p, &fcp, &kp, &nnp, &dpp, &evp, &evcp, &mrp, &missp,
                     &wr1p, &wr2p, &wz1p, &wz2p, &epp, &out, &Bblk };
    hipLaunchCooperativeKernel((const void*)k_fused, dim3(NB), dim3(BLK),
                               args, 0, stream);
}

// Round 3
// 123.128 us; speedup vs baseline: 1.8878x; 1.8878x over previous
//
#include <hip/hip_runtime.h>

#define T_N     1048576
#define BLK     256
#define S_OUT   4
#define R_BLOCK (BLK * S_OUT)        // 1024 rows per block
#define NB      (T_N / R_BLOCK)      // 1024 blocks -> 4 blocks/CU, 16 waves/CU
#define NTH     (T_N / S_OUT)        // 262144 threads
#define WARM    64                   // 0.71^64 ~ 3e-10 carry-error decay (do NOT shrink)
#define HALO    (WARM + 4)           // warm-up + max shift
#define SW(u)   ((u) + ((u) >> 2))   // stride-4 lane access -> dword stride 5, gcd(5,32)=1
#define NPREC   ((R_BLOCK + HALO + BLK - 1) / BLK)   // 5 staging iters (prec)
#define NCOEF   ((R_BLOCK + 4 + BLK - 1) / BLK)      // 5 staging iters (coeffs)

__device__ __forceinline__ float pp_step(float c, float p, float mr, float miss,
                                         float omev, float evc) {
    float last = (c > mr) ? fmaf(c - mr, miss, mr) : c;
    return fmaf(last + p, omev, -evc);
}

__global__ __launch_bounds__(BLK, 4) void k_main(
    const float* __restrict__ x,
    const float* __restrict__ f0p, const float* __restrict__ fcp,
    const float* __restrict__ kp,  const float* __restrict__ nnp,
    const float* __restrict__ dpp, const float* __restrict__ evp,
    const float* __restrict__ evcp,const float* __restrict__ mrp,
    const float* __restrict__ missp,
    const float* __restrict__ wr1p,const float* __restrict__ wr2p,
    const float* __restrict__ wz1p,const float* __restrict__ wz2p,
    const int*   __restrict__ epp,
    float* __restrict__ out, float* __restrict__ Bthr, float* __restrict__ Bblk)
{
    __shared__ float s_prec[SW(R_BLOCK + HALO - 1) + 1];
    __shared__ float s_cG[SW(R_BLOCK + 3) + 1];
    __shared__ float s_cA[SW(R_BLOCK + 3) + 1];
    __shared__ float s_B[BLK];
    // LDS ~17 KB; grid (4 blocks/CU) sets 16 waves/CU

    const int b = blockIdx.x, t = threadIdx.x;
    const int row0 = b * R_BLOCK;

    const float f0 = *f0p, fc = *fcp, kk = *kp, nn = *nnp;
    const float dp = *dpp, ev = *evp, evc = *evcp, mr = *mrp, miss = *missp;
    const float wr1 = *wr1p, wr2 = *wr2p, wz1 = *wz1p, wz2 = *wz2p;
    const int ep = *epp;
    const float omev = 1.0f - ev;
    const float cimp = 1.49f / nn;
    const float f0mfc = f0 - fc;

    const float rid = rintf(x[8]);                    // jnp.round == rint (half-even)
    const int shift = (rid == 3723.0f || rid == 870.0f) ? 1 : 4;
    const float pp0 = x[7] - x[6];                    // total_prec[0] - prec[0]

    // ---- staging, load phase: issue ALL global loads first, un-predicated ----
    // addresses are clamped into [0, T_N) so every load can issue without exec
    // masking; the VALUE is selected afterward (rows r<0 contribute zeros).
    float pv[NPREC];
    #pragma unroll
    for (int i = 0; i < NPREC; ++i) {
        int u = t + i * BLK;
        int r = row0 - HALO + u;
        int rc = r < 0 ? 0 : r;                       // u < R_BLOCK+HALO always here? no:
        if (u >= R_BLOCK + HALO) rc = 0;              // top guard only on last iter
        float ld = x[rc * 9 + 6];
        pv[i] = (u < R_BLOCK + HALO && r >= 0) ? ld : 0.0f;
    }
    float v0[NCOEF], v2[NCOEF], v3[NCOEF], v4[NCOEF], v7[NCOEF];
    #pragma unroll
    for (int i = 0; i < NCOEF; ++i) {
        int u = t + i * BLK;
        int r = row0 - 4 + u;
        bool ok = (u < R_BLOCK + 4) && (r >= 0);
        int rc = ok ? r : 0;
        const float* row = x + rc * 9;
        float l0 = row[0], l2 = row[2], l3 = row[3], l4 = row[4], l7 = row[7];
        v0[i] = ok ? l0 : 0.0f;
        v2[i] = ok ? l2 : 0.0f;
        v3[i] = ok ? l3 : 0.0f;
        v4[i] = ok ? l4 : 0.0f;
        v7[i] = ok ? l7 : 0.0f;
    }

    // ---- staging, compute + LDS-write phase ----
    #pragma unroll
    for (int i = 0; i < NPREC; ++i) {
        int u = t + i * BLK;
        if (u < R_BLOCK + HALO) s_prec[SW(u)] = pv[i];
    }
    #pragma unroll
    for (int i = 0; i < NCOEF; ++i) {
        int u = t + i * BLK;
        if (u < R_BLOCK + 4) {
            float ft = fmaf(f0mfc, __expf(-kk * v7[i]), fc);
            s_cG[SW(u)] = v0[i] * v3[i] * (1.0f - ft) * 0.001f;   // zero rows give 0
            s_cA[SW(u)] = sqrtf(v2[i] * v3[i]) * cimp * sqrtf(v4[i]);
        }
    }
    __syncthreads();

    // ---- scan-1: per-thread warm-up (contractive, slope <= 1-ev = 0.71/step) ----
    const int i0 = row0 + t * S_OUT;
    const int rb = i0 - shift;
    int rr = rb - WARM; if (rr < 0) rr = 0;
    float c = (rr == 0) ? pp0 : 0.0f;
    const int rs = (rb < 0) ? 0 : rb;
    for (; rr < rs; ++rr)
        c = pp_step(c, s_prec[SW(rr - row0 + HALO)], mr, miss, omev, evc);

    // ---- q + local (zero carry-in) scan-2; outputs held in registers ----
    float outl[S_OUT];
    float h = 0.0f;
    #pragma unroll
    for (int j = 0; j < S_OUT; ++j) {
        const int i = i0 + j;
        const int r = i - shift;
        float qs = 0.0f;
        if (r >= 0) {
            float pre = fmaxf(c, 0.0f);                 // relu'd prec_pre; carry stays raw
            int ci = r - row0 + 4;
            float qg = fmaxf(pre * s_cG[SW(ci)], 0.0f);
            float di = fmaxf(fmaf(pre, 0.001f, -dp), 0.0f);
            float qi = fmaxf(s_cA[SW(ci)] * __powf(di, 5.0f / 3.0f), 0.0f);
            qs = qg + qi;
            c = pp_step(c, s_prec[SW(r - row0 + HALO)], mr, miss, omev, evc);
        }
        h = fmaf(wr1, h, wr2 * qs);     // q_shift[0]=0 keeps h=0 through i=0 (matches ref)
        outl[j] = (ep > 10) ? fmaf(wz1, h, wz2 * qs) : qs;
    }

    // coalesced store: one float4 per thread
    float4* op = reinterpret_cast<float4*>(out + i0);
    op[0] = make_float4(outl[0], outl[1], outl[2], outl[3]);

    // thread aggregate (zero when epoch<=10 so fix-up kernel becomes a pure no-op)
    float Bv = (ep > 10) ? h : 0.0f;
    s_B[t] = Bv;
    Bthr[b * BLK + t] = Bv;
    __syncthreads();
    if (t == 0) {
        const float at = powf(wr1, (float)S_OUT);
        float acc = 0.0f;
        for (int u = 0; u < BLK; ++u) acc = fmaf(at, acc, s_B[u]);
        Bblk[b] = acc;
    }
}

// Cross-block carry propagation + correction: out[i0+j] += wz1 * wr1^(j+1) * h_in.
// Barrier-separated second launch (stream order), carries computed thread-parallel.
__global__ __launch_bounds__(BLK) void k_fix(
    float* __restrict__ out,
    const float* __restrict__ Bthr, const float* __restrict__ Bblk,
    const float* __restrict__ wr1p, const float* __restrict__ wz1p)
{
    __shared__ float sBb[NB];
    __shared__ float sB[BLK];
    __shared__ float carr[BLK];
    __shared__ float sred[BLK];
    const int b = blockIdx.x, t = threadIdx.x;
    const float wr1 = *wr1p, wz1 = *wz1p;
    for (int u = t; u < NB; u += BLK) sBb[u] = Bblk[u];
    sB[t] = Bthr[b * BLK + t];
    __syncthreads();

    // carry into block b = sum_{u<b} agg_u * ab^(b-1-u) — thread-parallel + tree reduce
    const float ab = powf(wr1, (float)R_BLOCK);     // wr1=1 -> exactly 1
    const float at = powf(wr1, (float)S_OUT);
    float partial = 0.0f;
    for (int u = t; u < b; u += BLK)                // <=4 iterations
        partial = fmaf(sBb[u], powf(ab, (float)(b - 1 - u)), partial);
    sred[t] = partial;
    __syncthreads();
    for (int off = BLK / 2; off > 0; off >>= 1) {
        if (t < off) sred[t] += sred[t + off];
        __syncthreads();
    }
    // per-thread carry: serial 256-fma prefix on t0 (~0.4 us, blocks in parallel)
    if (t == 0) {
        float cth = sred[0];
        for (int u = 0; u < BLK; ++u) { carr[u] = cth; cth = fmaf(at, cth, sB[u]); }
    }
    __syncthreads();

    float hin = carr[t];
    if (hin != 0.0f) {                  // epoch<=10 or true-zero carry: exact no-op
        float4* op = reinterpret_cast<float4*>(out + b * R_BLOCK + t * S_OUT);
        float4 v = op[0];
        float p = hin * wz1;
        p *= wr1; v.x += p; p *= wr1; v.y += p; p *= wr1; v.z += p; p *= wr1; v.w += p;
        op[0] = v;
    }
}

extern "C" void kernel_launch(void* const* d_in, const int* in_sizes, int n_in,
                              void* d_out, int out_size, void* d_ws, size_t ws_size,
                              hipStream_t stream) {
    const float* x = (const float*)d_in[0];
    float* out  = (float*)d_out;
    float* Bthr = (float*)d_ws;            // NTH floats (1 MB)
    float* Bblk = Bthr + NTH;              // NB floats

    k_main<<<NB, BLK, 0, stream>>>(x,
        (const float*)d_in[1],  (const float*)d_in[2],  (const float*)d_in[3],
        (const float*)d_in[4],  (const float*)d_in[5],  (const float*)d_in[6],
        (const float*)d_in[7],  (const float*)d_in[8],  (const float*)d_in[9],
        (const float*)d_in[10], (const float*)d_in[11], (const float*)d_in[12],
        (const float*)d_in[13], (const int*)d_in[14],
        out, Bthr, Bblk);

    k_fix<<<NB, BLK, 0, stream>>>(out, Bthr, Bblk,
        (const float*)d_in[10], (const float*)d_in[12]);
}

// Round 4
// 122.930 us; speedup vs baseline: 1.8909x; 1.0016x over previous
//
#include <hip/hip_runtime.h>

#define T_N     1048576
#define BLK     256
#define S_OUT   4
#define R_BLOCK (BLK * S_OUT)        // 1024 rows per block
#define NB      (T_N / R_BLOCK)      // 1024 blocks -> 4 blocks/CU, 16 waves/CU
#define NTH     (T_N / S_OUT)        // 262144 threads
#define WARM    64                   // 0.71^64 ~ 3e-10 carry-error decay (do NOT shrink)
#define HALO    (WARM + 4)           // warm-up + max shift
#define SW(u)   ((u) + ((u) >> 2))   // stride-4 lane access -> dword stride 5, gcd(5,32)=1
#define NPREC   ((R_BLOCK + HALO + BLK - 1) / BLK)   // 5 staging iters (prec)

__device__ __forceinline__ float pp_step(float c, float p, float mr, float miss,
                                         float omev, float evc) {
    float last = (c > mr) ? fmaf(c - mr, miss, mr) : c;
    return fmaf(last + p, omev, -evc);
}

__global__ __launch_bounds__(BLK, 4) void k_main(
    const float* __restrict__ x,
    const float* __restrict__ f0p, const float* __restrict__ fcp,
    const float* __restrict__ kp,  const float* __restrict__ nnp,
    const float* __restrict__ dpp, const float* __restrict__ evp,
    const float* __restrict__ evcp,const float* __restrict__ mrp,
    const float* __restrict__ missp,
    const float* __restrict__ wr1p,const float* __restrict__ wr2p,
    const float* __restrict__ wz1p,const float* __restrict__ wz2p,
    const int*   __restrict__ epp,
    float* __restrict__ out, float* __restrict__ Bthr, float* __restrict__ Bblk)
{
    // Only the prec column (17x halo reuse across threads) earns LDS. The q
    // coefficients are write-once-read-once BY THE SAME THREAD (shift is
    // grid-uniform), so they live in registers: no LDS round-trip, no extra
    // sync pressure, loads issued pre-barrier so they fly under the warm-up.
    __shared__ float s_prec[SW(R_BLOCK + HALO - 1) + 1];
    __shared__ float s_B[BLK];
    // LDS ~5.7 KB; grid (4 blocks/CU) sets 16 waves/CU

    const int b = blockIdx.x, t = threadIdx.x;
    const int row0 = b * R_BLOCK;

    const float f0 = *f0p, fc = *fcp, kk = *kp, nn = *nnp;
    const float dp = *dpp, ev = *evp, evc = *evcp, mr = *mrp, miss = *missp;
    const float wr1 = *wr1p, wr2 = *wr2p, wz1 = *wz1p, wz2 = *wz2p;
    const int ep = *epp;
    const float omev = 1.0f - ev;
    const float cimp = 1.49f / nn;
    const float f0mfc = f0 - fc;

    const float rid = rintf(x[8]);                    // jnp.round == rint (half-even)
    const int shift = (rid == 3723.0f || rid == 870.0f) ? 1 : 4;
    const float pp0 = x[7] - x[6];                    // total_prec[0] - prec[0]

    // ---- staging, load phase: prec column, un-predicated clamped loads ----
    float pv[NPREC];
    #pragma unroll
    for (int i = 0; i < NPREC; ++i) {
        int u = t + i * BLK;
        int r = row0 - HALO + u;
        int rc = r < 0 ? 0 : r;
        if (u >= R_BLOCK + HALO) rc = 0;              // top guard (keeps addr < T_N)
        float ld = x[rc * 9 + 6];
        pv[i] = (u < R_BLOCK + HALO && r >= 0) ? ld : 0.0f;
    }

    // ---- per-thread coefficient loads: rows [i0-shift, i0-shift+3] ----
    // Issued BEFORE the barrier so they stay in flight across LDS writes,
    // __syncthreads, and the serial warm-up chain (~700 cy of cover). The
    // prec staging above touches every 64B line of the slab, so these are
    // L1/L2 hits. Rows with r<0 are clamped; their values are never consumed
    // (the j-loop's r>=0 guard skips them).
    const int i0 = row0 + t * S_OUT;
    float g[S_OUT], im[S_OUT], ar[S_OUT], sl[S_OUT], tp[S_OUT];
    #pragma unroll
    for (int j = 0; j < S_OUT; ++j) {
        int r = i0 + j - shift;
        int rc = r < 0 ? 0 : r;                       // i0+j <= T_N-1 -> rc < T_N
        const float* row = x + rc * 9;
        g[j]  = row[0];
        im[j] = row[2];
        ar[j] = row[3];
        sl[j] = row[4];
        tp[j] = row[7];
    }

    // ---- staging, LDS-write phase ----
    #pragma unroll
    for (int i = 0; i < NPREC; ++i) {
        int u = t + i * BLK;
        if (u < R_BLOCK + HALO) s_prec[SW(u)] = pv[i];
    }
    __syncthreads();

    // ---- scan-1: per-thread warm-up (contractive, slope <= 1-ev = 0.71/step) ----
    const int rb = i0 - shift;
    int rr = rb - WARM; if (rr < 0) rr = 0;
    float c = (rr == 0) ? pp0 : 0.0f;
    const int rs = (rb < 0) ? 0 : rb;
    for (; rr < rs; ++rr)
        c = pp_step(c, s_prec[SW(rr - row0 + HALO)], mr, miss, omev, evc);

    // ---- q + local (zero carry-in) scan-2; outputs held in registers ----
    float outl[S_OUT];
    float h = 0.0f;
    #pragma unroll
    for (int j = 0; j < S_OUT; ++j) {
        const int r = i0 + j - shift;
        float qs = 0.0f;
        if (r >= 0) {
            float pre = fmaxf(c, 0.0f);                 // relu'd prec_pre; carry stays raw
            float ft  = fmaf(f0mfc, __expf(-kk * tp[j]), fc);
            float cg  = g[j] * ar[j] * (1.0f - ft) * 0.001f;
            float ca  = sqrtf(im[j] * ar[j]) * cimp * sqrtf(sl[j]);
            float qg  = fmaxf(pre * cg, 0.0f);
            float di  = fmaxf(fmaf(pre, 0.001f, -dp), 0.0f);
            float qi  = fmaxf(ca * __powf(di, 5.0f / 3.0f), 0.0f);
            qs = qg + qi;
            c = pp_step(c, s_prec[SW(r - row0 + HALO)], mr, miss, omev, evc);
        }
        h = fmaf(wr1, h, wr2 * qs);     // q_shift[0]=0 keeps h=0 through i=0 (matches ref)
        outl[j] = (ep > 10) ? fmaf(wz1, h, wz2 * qs) : qs;
    }

    // coalesced store: one float4 per thread
    float4* op = reinterpret_cast<float4*>(out + i0);
    op[0] = make_float4(outl[0], outl[1], outl[2], outl[3]);

    // thread aggregate (zero when epoch<=10 so fix-up kernel becomes a pure no-op)
    float Bv = (ep > 10) ? h : 0.0f;
    s_B[t] = Bv;
    Bthr[b * BLK + t] = Bv;
    __syncthreads();
    if (t == 0) {
        const float at = powf(wr1, (float)S_OUT);
        float acc = 0.0f;
        for (int u = 0; u < BLK; ++u) acc = fmaf(at, acc, s_B[u]);
        Bblk[b] = acc;
    }
}

// Cross-block carry propagation + correction: out[i0+j] += wz1 * wr1^(j+1) * h_in.
// Barrier-separated second launch (stream order), carries computed thread-parallel.
__global__ __launch_bounds__(BLK) void k_fix(
    float* __restrict__ out,
    const float* __restrict__ Bthr, const float* __restrict__ Bblk,
    const float* __restrict__ wr1p, const float* __restrict__ wz1p)
{
    __shared__ float sBb[NB];
    __shared__ float sB[BLK];
    __shared__ float carr[BLK];
    __shared__ float sred[BLK];
    const int b = blockIdx.x, t = threadIdx.x;
    const float wr1 = *wr1p, wz1 = *wz1p;
    for (int u = t; u < NB; u += BLK) sBb[u] = Bblk[u];
    sB[t] = Bthr[b * BLK + t];
    __syncthreads();

    // carry into block b = sum_{u<b} agg_u * ab^(b-1-u) — thread-parallel + tree reduce
    const float ab = powf(wr1, (float)R_BLOCK);     // wr1=1 -> exactly 1
    const float at = powf(wr1, (float)S_OUT);
    float partial = 0.0f;
    for (int u = t; u < b; u += BLK)                // <=4 iterations
        partial = fmaf(sBb[u], powf(ab, (float)(b - 1 - u)), partial);
    sred[t] = partial;
    __syncthreads();
    for (int off = BLK / 2; off > 0; off >>= 1) {
        if (t < off) sred[t] += sred[t + off];
        __syncthreads();
    }
    // per-thread carry: serial 256-fma prefix on t0 (~0.4 us, blocks in parallel)
    if (t == 0) {
        float cth = sred[0];
        for (int u = 0; u < BLK; ++u) { carr[u] = cth; cth = fmaf(at, cth, sB[u]); }
    }
    __syncthreads();

    float hin = carr[t];
    if (hin != 0.0f) {                  // epoch<=10 or true-zero carry: exact no-op
        float4* op = reinterpret_cast<float4*>(out + b * R_BLOCK + t * S_OUT);
        float4 v = op[0];
        float p = hin * wz1;
        p *= wr1; v.x += p; p *= wr1; v.y += p; p *= wr1; v.z += p; p *= wr1; v.w += p;
        op[0] = v;
    }
}

extern "C" void kernel_launch(void* const* d_in, const int* in_sizes, int n_in,
                              void* d_out, int out_size, void* d_ws, size_t ws_size,
                              hipStream_t stream) {
    const float* x = (const float*)d_in[0];
    float* out  = (float*)d_out;
    float* Bthr = (float*)d_ws;            // NTH floats (1 MB)
    float* Bblk = Bthr + NTH;              // NB floats

    k_main<<<NB, BLK, 0, stream>>>(x,
        (const float*)d_in[1],  (const float*)d_in[2],  (const float*)d_in[3],
        (const float*)d_in[4],  (const float*)d_in[5],  (const float*)d_in[6],
        (const float*)d_in[7],  (const float*)d_in[8],  (const float*)d_in[9],
        (const float*)d_in[10], (const float*)d_in[11], (const float*)d_in[12],
        (const float*)d_in[13], (const int*)d_in[14],
        out, Bthr, Bblk);

    k_fix<<<NB, BLK, 0, stream>>>(out, Bthr, Bblk,
        (const float*)d_in[10], (const float*)d_in[12]);
}